// Round 2
// baseline (3897.516 us; speedup 1.0000x reference)
//
#include <hip/hip_runtime.h>
#include <math.h>
#include <float.h>

#define NB     64      // batch
#define S_EN   50
#define S_DE   50
#define EMB_E  64
#define EMB_D  32
#define HID    32
#define G4     128     // 4*H
#define DE_VSZ 19000
#define OUT_B  (S_DE * DE_VSZ)

#define NG     4       // batch groups
#define JB     16      // batches per group (NG*JB = 64)
#define NSL    60      // vocab slices
#define NRS    320     // rows per slice (60*320 = 19200 >= 19000)
#define NBLK   (NG * NSL)   // 240 blocks <= 256 CUs -> co-residency by capacity
#define NTHR   640     // 10 waves; fc: 320 rows x 2 batch-octets = 640 tasks
#define WST    100     // LDS weight row stride in floats (400B, 16B-aligned)
#define POLL_CAP 50000 // bounded poll: deadlock -> terminating wrong answer

typedef unsigned long long ull;

__device__ __forceinline__ float sigmoidf_(float x) { return 1.0f / (1.0f + expf(-x)); }

// monotone float->uint: a<b <=> ordf(a)<ordf(b)
__device__ __forceinline__ unsigned ordf_(float f) {
    unsigned u = __float_as_uint(f);
    return (u & 0x80000000u) ? ~u : (u | 0x80000000u);
}

// Grid: 240 blocks = 4 batch-groups x 60 vocab slices. Block (g, isl):
//  - redundantly runs the LSTM for its group's 16 batches (bitwise identical
//    across the 60 slice-siblings: no block-index dependence in LSTM code),
//  - holds ONE fc row per thread in VGPRs (loaded once; zero fc_W re-reads),
//  - per decoder step publishes 16 packed keys [tag:6|ordf:32|~idx:15] via
//    RELAXED agent-scope 64-bit atomic stores (tag+payload in one word -> no
//    fences), polls its group's 60x16 keys until tags match, reduces argmax.
//  Skew between siblings is provably <=1 step -> parity-2 key buffering.
__global__ __launch_bounds__(NTHR, 3) void seq2seq_gsl(
    const int*   __restrict__ en_batch, const int* __restrict__ en_lens,
    const int*   __restrict__ de_batch,
    const float* __restrict__ en_emb,
    const float* __restrict__ eWih, const float* __restrict__ eWhh,
    const float* __restrict__ ebih, const float* __restrict__ ebhh,
    const float* __restrict__ de_emb,
    const float* __restrict__ dWih, const float* __restrict__ dWhh,
    const float* __restrict__ dbih, const float* __restrict__ dbhh,
    const float* __restrict__ fcW,  const float* __restrict__ fcb,
    float*       __restrict__ out,
    ull* kv)   // (2, NG, NSL, JB) packed keys, parity-buffered, zeroed pre-launch
{
    const int tid  = threadIdx.x;
    const int lane = tid & 63;
    const int wvi  = tid >> 6;           // wave 0..9
    const int bx   = blockIdx.x;
    const int g    = bx & 3;             // batch group
    const int isl  = bx >> 2;            // vocab slice 0..59

    __shared__ __align__(16) float s_w[G4 * WST];   // 51.2 KB enc/dec weights
    __shared__ __align__(16) float s_xh[JB][104];   // x|h per batch (enc: h@64, dec: h@32)
    __shared__ __align__(16) float s_hT[HID][JB];   // h transposed for fc
    __shared__ ull  s_red[10 * JB];                 // per-wave per-batch keys
    __shared__ int  s_tok[JB];
    __shared__ int  s_len[JB];

    // ---- zero out[:, 0, :] ----
    for (int idx = bx * NTHR + tid; idx < NB * (DE_VSZ / 4); idx += NBLK * NTHR) {
        const int bb = idx / (DE_VSZ / 4);
        const int qq = idx - bb * (DE_VSZ / 4);
        *(float4*)(out + (size_t)bb * OUT_B + (size_t)qq * 4) = make_float4(0.f, 0.f, 0.f, 0.f);
    }

    // ---- stage encoder weights: row r = eWih[r][0..63] | eWhh[r][0..31] ----
    for (int idx = tid; idx < G4 * 96; idx += NTHR) {
        const int row = idx / 96, k = idx - row * 96;
        s_w[row * WST + k] = (k < EMB_E) ? eWih[row * EMB_E + k]
                                         : eWhh[row * HID + (k - EMB_E)];
    }
    if (tid < JB) {
        s_len[tid] = en_lens[g * JB + tid];
        s_tok[tid] = de_batch[(g * JB + tid) * S_DE + 0];
    }

    // LSTM thread mapping: (jb = tid>>5, u = tid&31) for tid < 512.
    const int jb = tid >> 5;
    const int u  = tid & 31;
    float ebs0=0,ebs1=0,ebs2=0,ebs3=0, dbs0=0,dbs1=0,dbs2=0,dbs3=0;
    float creg = 0.f;
    if (tid < JB * HID) {
        ebs0 = ebih[u]      + ebhh[u];
        ebs1 = ebih[32 + u] + ebhh[32 + u];
        ebs2 = ebih[64 + u] + ebhh[64 + u];
        ebs3 = ebih[96 + u] + ebhh[96 + u];
        dbs0 = dbih[u]      + dbhh[u];
        dbs1 = dbih[32 + u] + dbhh[32 + u];
        dbs2 = dbih[64 + u] + dbhh[64 + u];
        dbs3 = dbih[96 + u] + dbhh[96 + u];
        s_xh[jb][64 + u] = 0.f;          // encoder h init
    }

    // ---- fc: one (row, batch-octet) per thread; weights live in VGPRs ----
    const int  frow   = tid >> 1;                 // 0..319
    const int  hf     = tid & 1;                  // batch octet
    const int  r      = isl * NRS + frow;
    const bool rvalid = (r < DE_VSZ);
    float fw[32]; float fb = 0.f;
    {
        const float4* w4p = (const float4*)&fcW[(size_t)(rvalid ? r : 0) * HID];
        #pragma unroll
        for (int c = 0; c < 8; ++c) {
            const float4 v = w4p[c];
            fw[c*4+0] = v.x; fw[c*4+1] = v.y; fw[c*4+2] = v.z; fw[c*4+3] = v.w;
        }
        if (rvalid) fb = fcb[r];
    }
    __syncthreads();

    int maxlen = 1;
    for (int j = 0; j < JB; ++j) maxlen = max(maxlen, s_len[j]);
    const int mylen = (tid < JB * HID) ? s_len[jb] : 0;

    // ---- encoder: 16 batches, mask t < len[jb] (matches jnp.where(valid)) ----
    for (int t = 0; t < maxlen; ++t) {
        if (tid < JB * 16) {
            const int jj = tid >> 4, q = tid & 15;
            const int etok = en_batch[(g * JB + jj) * S_EN + t];
            *(float4*)&s_xh[jj][q * 4] = *(const float4*)&en_emb[(size_t)etok * EMB_E + q * 4];
        }
        __syncthreads();
        float cnew = 0.f, hnew = 0.f;
        if (tid < JB * HID) {
            float a0 = ebs0, a1 = ebs1, a2 = ebs2, a3 = ebs3;
            #pragma unroll
            for (int kc = 0; kc < 24; ++kc) {
                const float4 xh = *(const float4*)&s_xh[jb][kc * 4];
                const float4 w0 = *(const float4*)&s_w[(u     ) * WST + kc * 4];
                const float4 w1 = *(const float4*)&s_w[(u + 32) * WST + kc * 4];
                const float4 w2 = *(const float4*)&s_w[(u + 64) * WST + kc * 4];
                const float4 w3 = *(const float4*)&s_w[(u + 96) * WST + kc * 4];
                a0 = fmaf(xh.x,w0.x,a0); a0 = fmaf(xh.y,w0.y,a0); a0 = fmaf(xh.z,w0.z,a0); a0 = fmaf(xh.w,w0.w,a0);
                a1 = fmaf(xh.x,w1.x,a1); a1 = fmaf(xh.y,w1.y,a1); a1 = fmaf(xh.z,w1.z,a1); a1 = fmaf(xh.w,w1.w,a1);
                a2 = fmaf(xh.x,w2.x,a2); a2 = fmaf(xh.y,w2.y,a2); a2 = fmaf(xh.z,w2.z,a2); a2 = fmaf(xh.w,w2.w,a2);
                a3 = fmaf(xh.x,w3.x,a3); a3 = fmaf(xh.y,w3.y,a3); a3 = fmaf(xh.z,w3.z,a3); a3 = fmaf(xh.w,w3.w,a3);
            }
            const float ii = sigmoidf_(a0), ff = sigmoidf_(a1);
            const float gg = tanhf(a2),     oo = sigmoidf_(a3);
            cnew = ff * creg + ii * gg;
            hnew = oo * tanhf(cnew);
        }
        __syncthreads();
        if (tid < JB * HID && t < mylen) {
            creg = cnew;
            s_xh[jb][64 + u] = hnew;
        }
        __syncthreads();
    }

    // ---- handoff: h -> decoder slot [32+u] + s_hT; restage decoder weights ----
    float hcur = 0.f;
    if (tid < JB * HID) hcur = s_xh[jb][64 + u];   // read [64..95]
    for (int idx = tid; idx < G4 * 64; idx += NTHR) {
        const int row = idx >> 6, k = idx & 63;
        s_w[row * WST + k] = (k < HID) ? dWih[row * HID + k]
                                       : dWhh[row * HID + (k - HID)];
    }
    if (tid < JB * HID) {                          // write [32..63] (disjoint)
        s_xh[jb][32 + u] = hcur;
        s_hT[u][jb]      = hcur;
    }
    __syncthreads();

    // ---- decoder: 49 steps ----
    for (int s = 1; s < S_DE; ++s) {
        // (a) x = de_emb[tok]
        if (tid < JB * 8) {
            const int jj = tid >> 3, q = tid & 7;
            const int tk = s_tok[jj];
            *(float4*)&s_xh[jj][q * 4] = *(const float4*)&de_emb[(size_t)tk * EMB_D + q * 4];
        }
        __syncthreads();

        // (b) gates fully in regs (thread owns (jb,u): 4 gates + cell state)
        float hnew = 0.f;
        if (tid < JB * HID) {
            float a0 = dbs0, a1 = dbs1, a2 = dbs2, a3 = dbs3;
            #pragma unroll
            for (int kc = 0; kc < 16; ++kc) {
                const float4 xh = *(const float4*)&s_xh[jb][kc * 4];
                const float4 w0 = *(const float4*)&s_w[(u     ) * WST + kc * 4];
                const float4 w1 = *(const float4*)&s_w[(u + 32) * WST + kc * 4];
                const float4 w2 = *(const float4*)&s_w[(u + 64) * WST + kc * 4];
                const float4 w3 = *(const float4*)&s_w[(u + 96) * WST + kc * 4];
                a0 = fmaf(xh.x,w0.x,a0); a0 = fmaf(xh.y,w0.y,a0); a0 = fmaf(xh.z,w0.z,a0); a0 = fmaf(xh.w,w0.w,a0);
                a1 = fmaf(xh.x,w1.x,a1); a1 = fmaf(xh.y,w1.y,a1); a1 = fmaf(xh.z,w1.z,a1); a1 = fmaf(xh.w,w1.w,a1);
                a2 = fmaf(xh.x,w2.x,a2); a2 = fmaf(xh.y,w2.y,a2); a2 = fmaf(xh.z,w2.z,a2); a2 = fmaf(xh.w,w2.w,a2);
                a3 = fmaf(xh.x,w3.x,a3); a3 = fmaf(xh.y,w3.y,a3); a3 = fmaf(xh.z,w3.z,a3); a3 = fmaf(xh.w,w3.w,a3);
            }
            const float ii = sigmoidf_(a0), ff = sigmoidf_(a1);
            const float gg = tanhf(a2),     oo = sigmoidf_(a3);
            creg = ff * creg + ii * gg;
            hnew = oo * tanhf(creg);
        }
        __syncthreads();
        if (tid < JB * HID) { s_xh[jb][32 + u] = hnew; s_hT[u][jb] = hnew; }
        __syncthreads();

        // (c) fc: 8 batch-logits per thread, w in VGPRs, h broadcast from LDS
        float acc[8];
        #pragma unroll
        for (int j = 0; j < 8; ++j) acc[j] = fb;
        #pragma unroll
        for (int k = 0; k < 32; ++k) {
            const float wk = fw[k];
            const float4 ha = *(const float4*)&s_hT[k][hf * 8];
            const float4 hb = *(const float4*)&s_hT[k][hf * 8 + 4];
            acc[0] = fmaf(wk, ha.x, acc[0]); acc[1] = fmaf(wk, ha.y, acc[1]);
            acc[2] = fmaf(wk, ha.z, acc[2]); acc[3] = fmaf(wk, ha.w, acc[3]);
            acc[4] = fmaf(wk, hb.x, acc[4]); acc[5] = fmaf(wk, hb.y, acc[5]);
            acc[6] = fmaf(wk, hb.z, acc[6]); acc[7] = fmaf(wk, hb.w, acc[7]);
        }
        if (rvalid) {
            float* od = out + (size_t)(g * JB + hf * 8) * OUT_B + (size_t)s * DE_VSZ + r;
            #pragma unroll
            for (int j = 0; j < 8; ++j) od[(size_t)j * OUT_B] = acc[j];
        }
        // per-batch keys, reduce over the 32 same-octet lanes (even xor offsets)
        #pragma unroll
        for (int j = 0; j < 8; ++j) {
            ull kj = rvalid ? (((ull)ordf_(acc[j]) << 15) | (unsigned)((~r) & 0x7FFF)) : 0ull;
            #pragma unroll
            for (int off = 2; off <= 32; off <<= 1) {
                const ull ok = __shfl_xor(kj, off);
                if (ok > kj) kj = ok;
            }
            if (lane < 2) s_red[(wvi * 2 + hf) * 8 + j] = kj;  // lane0:hf0, lane1:hf1
        }
        __syncthreads();

        const int par = s & 1;
        if (tid < JB) {            // final reduce over 10 waves; publish key
            const int bhf = tid >> 3, bj = tid & 7;
            ull m = s_red[bhf * 8 + bj];
            for (int w = 1; w < 10; ++w) {
                const ull k2 = s_red[(w * 2 + bhf) * 8 + bj];
                if (k2 > m) m = k2;
            }
            const ull stored = ((ull)s << 47) | m;   // tag:6 @47 | ordf:32 @15 | ~idx:15
            __hip_atomic_store(&kv[(((size_t)par * NG + g) * NSL + isl) * JB + tid],
                               stored, __ATOMIC_RELAXED, __HIP_MEMORY_SCOPE_AGENT);
        }
        if (s == S_DE - 1) break;

        // (d) poll group's 60x16 keys: thread (pbi=jb, pj=u) covers slices pj, 32+pj
        ull k0 = 0, k1 = 0;
        int iter = 0;
        for (;;) {
            int ok = 1;
            if (tid < JB * HID) {
                k0 = __hip_atomic_load(&kv[(((size_t)par * NG + g) * NSL + u) * JB + jb],
                                       __ATOMIC_RELAXED, __HIP_MEMORY_SCOPE_AGENT);
                ok = ((int)(k0 >> 47) == s);
                if (u < NSL - 32) {
                    k1 = __hip_atomic_load(&kv[(((size_t)par * NG + g) * NSL + (32 + u)) * JB + jb],
                                           __ATOMIC_RELAXED, __HIP_MEMORY_SCOPE_AGENT);
                    ok &= ((int)(k1 >> 47) == s);
                }
            }
            if (__syncthreads_and(ok)) break;
            if (++iter > POLL_CAP) break;   // safety net: never hang the queue
            __builtin_amdgcn_s_sleep(2);
        }

        // (e) token = argmax over 60 slices (32-lane xor reduce within batch group)
        if (tid < JB * HID) {
            ull m = ((u < NSL - 32) && k1 > k0) ? k1 : k0;
            #pragma unroll
            for (int off = 1; off < 32; off <<= 1) {
                const ull ok = __shfl_xor(m, off);
                if (ok > m) m = ok;
            }
            if (u == 0) s_tok[jb] = 0x7FFF & (int)(~(unsigned)m);
        }
        __syncthreads();
    }
}

extern "C" void kernel_launch(void* const* d_in, const int* in_sizes, int n_in,
                              void* d_out, int out_size, void* d_ws, size_t ws_size,
                              hipStream_t stream) {
    (void)in_sizes; (void)n_in; (void)out_size; (void)ws_size;
    const int*   en_batch = (const int*)  d_in[0];
    const int*   en_lens  = (const int*)  d_in[1];
    const int*   de_batch = (const int*)  d_in[2];
    const float* en_emb   = (const float*)d_in[3];
    const float* eWih     = (const float*)d_in[4];
    const float* eWhh     = (const float*)d_in[5];
    const float* ebih     = (const float*)d_in[6];
    const float* ebhh     = (const float*)d_in[7];
    const float* de_emb   = (const float*)d_in[8];
    const float* dWih     = (const float*)d_in[9];
    const float* dWhh     = (const float*)d_in[10];
    const float* dbih     = (const float*)d_in[11];
    const float* dbhh     = (const float*)d_in[12];
    const float* fcW      = (const float*)d_in[13];
    const float* fcb      = (const float*)d_in[14];
    float* out = (float*)d_out;

    ull* kv = (ull*)d_ws;                      // 2*4*60*16*8 = 61,440 B
    hipMemsetAsync(d_ws, 0, 65536, stream);    // tag 0 != any step s>=1

    seq2seq_gsl<<<NBLK, NTHR, 0, stream>>>(
        en_batch, en_lens, de_batch, en_emb, eWih, eWhh, ebih, ebhh,
        de_emb, dWih, dWhh, dbih, dbhh, fcW, fcb, out, kv);
}

// Round 3
// 3872.456 us; speedup vs baseline: 1.0065x; 1.0065x over previous
//
#include <hip/hip_runtime.h>
#include <math.h>
#include <float.h>

#define NB     64      // batch
#define S_EN   50
#define S_DE   50
#define EMB_E  64
#define EMB_D  32
#define HID    32
#define G4     128     // 4*H
#define DE_VSZ 19000
#define OUT_B  (S_DE * DE_VSZ)

#define NG     4       // batch groups
#define JB     16      // batches per group (NG*JB = 64)
#define NSL    60      // vocab slices
#define NRS    320     // rows per slice (60*320 = 19200 >= 19000)
#define NBLK   (NG * NSL)   // 240 blocks <= 256 CUs -> co-residency by capacity
#define NTHR   640     // 10 waves; fc: 320 rows x 2 batch-octets = 640 tasks
#define WST    100     // LDS weight row stride in floats (400B, 16B-aligned)
#define KVSTR  64      // kv slice-stride per (g,jb) row (60 used, 64 for lines)
#define POLL_CAP 200000 // bounded poll: deadlock -> terminating wrong answer

typedef unsigned long long ull;

__device__ __forceinline__ float sigmoidf_(float x) { return 1.0f / (1.0f + expf(-x)); }

// monotone float->uint: a<b <=> ordf(a)<ordf(b)
__device__ __forceinline__ unsigned ordf_(float f) {
    unsigned u = __float_as_uint(f);
    return (u & 0x80000000u) ? ~u : (u | 0x80000000u);
}

// Grid: 240 blocks = 4 batch-groups x 60 vocab slices. Block (g, isl):
//  - redundantly runs the LSTM for its group's 16 batches (bitwise identical
//    across the 60 slice-siblings),
//  - holds ONE fc row per thread in VGPRs (loaded once; zero fc_W re-reads),
//  - publishes 16 packed keys [tag:6|ordf:32|~idx:15] (relaxed agent atomics).
// TWO-HOP rendezvous (fixes round-2's 13 GB poll-storm): leader block (isl==0)
// of each group polls the 60x16 keys (coalesced: 8 KB/poll), reduces argmax,
// publishes 16 token words [tag|token]; siblings poll ONE 128-B line with 16
// lanes of wave 0. Every cross-block link is a single-word tagged value ->
// no fences anywhere. Chain-gating (slice can't publish s+1 before consuming
// token s; leader can't publish s+1 before reading all keys s+1) -> no ABA,
// no parity buffers needed.
__global__ __launch_bounds__(NTHR, 3) void seq2seq_2hop(
    const int*   __restrict__ en_batch, const int* __restrict__ en_lens,
    const int*   __restrict__ de_batch,
    const float* __restrict__ en_emb,
    const float* __restrict__ eWih, const float* __restrict__ eWhh,
    const float* __restrict__ ebih, const float* __restrict__ ebhh,
    const float* __restrict__ de_emb,
    const float* __restrict__ dWih, const float* __restrict__ dWhh,
    const float* __restrict__ dbih, const float* __restrict__ dbhh,
    const float* __restrict__ fcW,  const float* __restrict__ fcb,
    float*       __restrict__ out,
    ull* kv,   // (NG, JB, KVSTR) packed slice keys
    ull* tk)   // (NG, JB) leader-reduced token words [tag:32|token:32]
{
    const int tid  = threadIdx.x;
    const int lane = tid & 63;
    const int wvi  = tid >> 6;           // wave 0..9
    const int bx   = blockIdx.x;
    const int g    = bx & 3;             // batch group
    const int isl  = bx >> 2;            // vocab slice 0..59

    __shared__ __align__(16) float s_w[G4 * WST];   // 51.2 KB enc/dec weights
    __shared__ __align__(16) float s_xh[JB][104];   // x|h per batch (enc: h@64, dec: h@32)
    __shared__ __align__(16) float s_hT[HID][JB];   // h transposed for fc
    __shared__ ull  s_red[10 * JB];                 // per-wave per-batch keys
    __shared__ int  s_tok[JB];
    __shared__ int  s_len[JB];

    // ---- zero out[:, 0, :] ----
    for (int idx = bx * NTHR + tid; idx < NB * (DE_VSZ / 4); idx += NBLK * NTHR) {
        const int bb = idx / (DE_VSZ / 4);
        const int qq = idx - bb * (DE_VSZ / 4);
        *(float4*)(out + (size_t)bb * OUT_B + (size_t)qq * 4) = make_float4(0.f, 0.f, 0.f, 0.f);
    }

    // ---- stage encoder weights: row r = eWih[r][0..63] | eWhh[r][0..31] ----
    for (int idx = tid; idx < G4 * 96; idx += NTHR) {
        const int row = idx / 96, k = idx - row * 96;
        s_w[row * WST + k] = (k < EMB_E) ? eWih[row * EMB_E + k]
                                         : eWhh[row * HID + (k - EMB_E)];
    }
    if (tid < JB) {
        s_len[tid] = en_lens[g * JB + tid];
        s_tok[tid] = de_batch[(g * JB + tid) * S_DE + 0];
    }

    // LSTM thread mapping: (jb = tid>>5, u = tid&31) for tid < 512.
    const int jb = tid >> 5;
    const int u  = tid & 31;
    float ebs0=0,ebs1=0,ebs2=0,ebs3=0, dbs0=0,dbs1=0,dbs2=0,dbs3=0;
    float creg = 0.f;
    if (tid < JB * HID) {
        ebs0 = ebih[u]      + ebhh[u];
        ebs1 = ebih[32 + u] + ebhh[32 + u];
        ebs2 = ebih[64 + u] + ebhh[64 + u];
        ebs3 = ebih[96 + u] + ebhh[96 + u];
        dbs0 = dbih[u]      + dbhh[u];
        dbs1 = dbih[32 + u] + dbhh[32 + u];
        dbs2 = dbih[64 + u] + dbhh[64 + u];
        dbs3 = dbih[96 + u] + dbhh[96 + u];
        s_xh[jb][64 + u] = 0.f;          // encoder h init
    }

    // ---- fc: one (row, batch-octet) per thread; weights live in VGPRs ----
    const int  frow   = tid >> 1;                 // 0..319
    const int  hf     = tid & 1;                  // batch octet
    const int  r      = isl * NRS + frow;
    const bool rvalid = (r < DE_VSZ);
    float fw[32]; float fb = 0.f;
    {
        const float4* w4p = (const float4*)&fcW[(size_t)(rvalid ? r : 0) * HID];
        #pragma unroll
        for (int c = 0; c < 8; ++c) {
            const float4 v = w4p[c];
            fw[c*4+0] = v.x; fw[c*4+1] = v.y; fw[c*4+2] = v.z; fw[c*4+3] = v.w;
        }
        if (rvalid) fb = fcb[r];
    }
    __syncthreads();

    int maxlen = 1;
    for (int j = 0; j < JB; ++j) maxlen = max(maxlen, s_len[j]);
    const int mylen = (tid < JB * HID) ? s_len[jb] : 0;

    // ---- encoder: 16 batches, mask t < len[jb] (matches jnp.where(valid)) ----
    for (int t = 0; t < maxlen; ++t) {
        if (tid < JB * 16) {
            const int jj = tid >> 4, q = tid & 15;
            const int etok = en_batch[(g * JB + jj) * S_EN + t];
            *(float4*)&s_xh[jj][q * 4] = *(const float4*)&en_emb[(size_t)etok * EMB_E + q * 4];
        }
        __syncthreads();
        float cnew = 0.f, hnew = 0.f;
        if (tid < JB * HID) {
            float a0 = ebs0, a1 = ebs1, a2 = ebs2, a3 = ebs3;
            #pragma unroll
            for (int kc = 0; kc < 24; ++kc) {
                const float4 xh = *(const float4*)&s_xh[jb][kc * 4];
                const float4 w0 = *(const float4*)&s_w[(u     ) * WST + kc * 4];
                const float4 w1 = *(const float4*)&s_w[(u + 32) * WST + kc * 4];
                const float4 w2 = *(const float4*)&s_w[(u + 64) * WST + kc * 4];
                const float4 w3 = *(const float4*)&s_w[(u + 96) * WST + kc * 4];
                a0 = fmaf(xh.x,w0.x,a0); a0 = fmaf(xh.y,w0.y,a0); a0 = fmaf(xh.z,w0.z,a0); a0 = fmaf(xh.w,w0.w,a0);
                a1 = fmaf(xh.x,w1.x,a1); a1 = fmaf(xh.y,w1.y,a1); a1 = fmaf(xh.z,w1.z,a1); a1 = fmaf(xh.w,w1.w,a1);
                a2 = fmaf(xh.x,w2.x,a2); a2 = fmaf(xh.y,w2.y,a2); a2 = fmaf(xh.z,w2.z,a2); a2 = fmaf(xh.w,w2.w,a2);
                a3 = fmaf(xh.x,w3.x,a3); a3 = fmaf(xh.y,w3.y,a3); a3 = fmaf(xh.z,w3.z,a3); a3 = fmaf(xh.w,w3.w,a3);
            }
            const float ii = sigmoidf_(a0), ff = sigmoidf_(a1);
            const float gg = tanhf(a2),     oo = sigmoidf_(a3);
            cnew = ff * creg + ii * gg;
            hnew = oo * tanhf(cnew);
        }
        __syncthreads();
        if (tid < JB * HID && t < mylen) {
            creg = cnew;
            s_xh[jb][64 + u] = hnew;
        }
        __syncthreads();
    }

    // ---- handoff: h -> decoder slot [32+u] + s_hT; restage decoder weights ----
    float hcur = 0.f;
    if (tid < JB * HID) hcur = s_xh[jb][64 + u];   // read [64..95]
    for (int idx = tid; idx < G4 * 64; idx += NTHR) {
        const int row = idx >> 6, k = idx & 63;
        s_w[row * WST + k] = (k < HID) ? dWih[row * HID + k]
                                       : dWhh[row * HID + (k - HID)];
    }
    if (tid < JB * HID) {                          // write [32..63] (disjoint)
        s_xh[jb][32 + u] = hcur;
        s_hT[u][jb]      = hcur;
    }
    __syncthreads();

    // ---- decoder: 49 steps ----
    for (int s = 1; s < S_DE; ++s) {
        // (a) x = de_emb[tok]
        if (tid < JB * 8) {
            const int jj = tid >> 3, q = tid & 7;
            const int tk_ = s_tok[jj];
            *(float4*)&s_xh[jj][q * 4] = *(const float4*)&de_emb[(size_t)tk_ * EMB_D + q * 4];
        }
        __syncthreads();

        // (b) gates fully in regs (thread owns (jb,u): 4 gates + cell state)
        float hnew = 0.f;
        if (tid < JB * HID) {
            float a0 = dbs0, a1 = dbs1, a2 = dbs2, a3 = dbs3;
            #pragma unroll
            for (int kc = 0; kc < 16; ++kc) {
                const float4 xh = *(const float4*)&s_xh[jb][kc * 4];
                const float4 w0 = *(const float4*)&s_w[(u     ) * WST + kc * 4];
                const float4 w1 = *(const float4*)&s_w[(u + 32) * WST + kc * 4];
                const float4 w2 = *(const float4*)&s_w[(u + 64) * WST + kc * 4];
                const float4 w3 = *(const float4*)&s_w[(u + 96) * WST + kc * 4];
                a0 = fmaf(xh.x,w0.x,a0); a0 = fmaf(xh.y,w0.y,a0); a0 = fmaf(xh.z,w0.z,a0); a0 = fmaf(xh.w,w0.w,a0);
                a1 = fmaf(xh.x,w1.x,a1); a1 = fmaf(xh.y,w1.y,a1); a1 = fmaf(xh.z,w1.z,a1); a1 = fmaf(xh.w,w1.w,a1);
                a2 = fmaf(xh.x,w2.x,a2); a2 = fmaf(xh.y,w2.y,a2); a2 = fmaf(xh.z,w2.z,a2); a2 = fmaf(xh.w,w2.w,a2);
                a3 = fmaf(xh.x,w3.x,a3); a3 = fmaf(xh.y,w3.y,a3); a3 = fmaf(xh.z,w3.z,a3); a3 = fmaf(xh.w,w3.w,a3);
            }
            const float ii = sigmoidf_(a0), ff = sigmoidf_(a1);
            const float gg = tanhf(a2),     oo = sigmoidf_(a3);
            creg = ff * creg + ii * gg;
            hnew = oo * tanhf(creg);
        }
        __syncthreads();
        if (tid < JB * HID) { s_xh[jb][32 + u] = hnew; s_hT[u][jb] = hnew; }
        __syncthreads();

        // (c) fc: 8 batch-logits per thread, w in VGPRs, h broadcast from LDS
        float acc[8];
        #pragma unroll
        for (int j = 0; j < 8; ++j) acc[j] = fb;
        #pragma unroll
        for (int k = 0; k < 32; ++k) {
            const float wk = fw[k];
            const float4 ha = *(const float4*)&s_hT[k][hf * 8];
            const float4 hb = *(const float4*)&s_hT[k][hf * 8 + 4];
            acc[0] = fmaf(wk, ha.x, acc[0]); acc[1] = fmaf(wk, ha.y, acc[1]);
            acc[2] = fmaf(wk, ha.z, acc[2]); acc[3] = fmaf(wk, ha.w, acc[3]);
            acc[4] = fmaf(wk, hb.x, acc[4]); acc[5] = fmaf(wk, hb.y, acc[5]);
            acc[6] = fmaf(wk, hb.z, acc[6]); acc[7] = fmaf(wk, hb.w, acc[7]);
        }
        if (rvalid) {
            float* od = out + (size_t)(g * JB + hf * 8) * OUT_B + (size_t)s * DE_VSZ + r;
            #pragma unroll
            for (int j = 0; j < 8; ++j) od[(size_t)j * OUT_B] = acc[j];
        }
        if (s == S_DE - 1) break;   // final step: no one consumes these keys

        // per-batch keys, reduce over the 32 same-octet lanes (even xor offsets)
        #pragma unroll
        for (int j = 0; j < 8; ++j) {
            ull kj = rvalid ? (((ull)ordf_(acc[j]) << 15) | (unsigned)((~r) & 0x7FFF)) : 0ull;
            #pragma unroll
            for (int off = 2; off <= 32; off <<= 1) {
                const ull ok = __shfl_xor(kj, off);
                if (ok > kj) kj = ok;
            }
            if (lane < 2) s_red[(wvi * 2 + hf) * 8 + j] = kj;  // lane0:hf0, lane1:hf1
        }
        __syncthreads();

        if (tid < JB) {            // final reduce over 10 waves; publish tagged key
            const int bhf = tid >> 3, bj = tid & 7;
            ull m = s_red[bhf * 8 + bj];
            for (int w = 1; w < 10; ++w) {
                const ull k2 = s_red[(w * 2 + bhf) * 8 + bj];
                if (k2 > m) m = k2;
            }
            // tag:6 @47 | ordf:32 @15 | ~idx:15 ; batch index == tid
            __hip_atomic_store(&kv[((size_t)g * JB + tid) * KVSTR + isl],
                               ((ull)s << 47) | m,
                               __ATOMIC_RELAXED, __HIP_MEMORY_SCOPE_AGENT);
        }

        if (isl == 0) {
            // ---- leader: poll all 60x16 keys (coalesced 8 KB), reduce, publish
            ull k0 = 0, k1 = 0;
            int iter = 0;
            const size_t kbase = ((size_t)g * JB + jb) * KVSTR;   // jb = tid>>5
            for (;;) {
                int ok = 1;
                if (tid < JB * HID) {
                    k0 = __hip_atomic_load(&kv[kbase + u], __ATOMIC_RELAXED, __HIP_MEMORY_SCOPE_AGENT);
                    ok = ((int)(k0 >> 47) == s);
                    if (u < NSL - 32) {
                        k1 = __hip_atomic_load(&kv[kbase + 32 + u], __ATOMIC_RELAXED, __HIP_MEMORY_SCOPE_AGENT);
                        ok &= ((int)(k1 >> 47) == s);
                    }
                }
                if (__syncthreads_and(ok)) break;
                if (++iter > POLL_CAP) break;   // safety: never hang the queue
                __builtin_amdgcn_s_sleep(2);
            }
            if (tid < JB * HID) {
                ull m = ((u < NSL - 32) && k1 > k0) ? k1 : k0;
                #pragma unroll
                for (int off = 1; off < 32; off <<= 1) {
                    const ull ok2 = __shfl_xor(m, off);
                    if (ok2 > m) m = ok2;
                }
                if (u == 0) {
                    const int token = (int)((~(unsigned)m) & 0x7FFF);
                    s_tok[jb] = token;
                    __hip_atomic_store(&tk[g * JB + jb],
                                       ((ull)s << 32) | (unsigned)token,
                                       __ATOMIC_RELAXED, __HIP_MEMORY_SCOPE_AGENT);
                }
            }
            __syncthreads();
        } else {
            // ---- sibling: poll ONE 128-B line (16 token words) with wave 0
            ull tw = 0;
            int iter = 0;
            for (;;) {
                int ok = 1;
                if (wvi == 0 && lane < JB) {
                    tw = __hip_atomic_load(&tk[g * JB + lane], __ATOMIC_RELAXED, __HIP_MEMORY_SCOPE_AGENT);
                    ok = ((int)(tw >> 32) == s);
                }
                if (__syncthreads_and(ok)) break;
                if (++iter > POLL_CAP) break;   // safety: never hang the queue
                __builtin_amdgcn_s_sleep(2);
            }
            if (wvi == 0 && lane < JB) s_tok[lane] = (int)(tw & 0x7FFF);
            __syncthreads();
        }
    }
}

extern "C" void kernel_launch(void* const* d_in, const int* in_sizes, int n_in,
                              void* d_out, int out_size, void* d_ws, size_t ws_size,
                              hipStream_t stream) {
    (void)in_sizes; (void)n_in; (void)out_size; (void)ws_size;
    const int*   en_batch = (const int*)  d_in[0];
    const int*   en_lens  = (const int*)  d_in[1];
    const int*   de_batch = (const int*)  d_in[2];
    const float* en_emb   = (const float*)d_in[3];
    const float* eWih     = (const float*)d_in[4];
    const float* eWhh     = (const float*)d_in[5];
    const float* ebih     = (const float*)d_in[6];
    const float* ebhh     = (const float*)d_in[7];
    const float* de_emb   = (const float*)d_in[8];
    const float* dWih     = (const float*)d_in[9];
    const float* dWhh     = (const float*)d_in[10];
    const float* dbih     = (const float*)d_in[11];
    const float* dbhh     = (const float*)d_in[12];
    const float* fcW      = (const float*)d_in[13];
    const float* fcb      = (const float*)d_in[14];
    float* out = (float*)d_out;

    ull* kv = (ull*)d_ws;                           // 4*16*64*8 = 32 KB
    ull* tk = (ull*)((char*)d_ws + 32768);          // 4*16*8   = 512 B
    hipMemsetAsync(d_ws, 0, 40960, stream);         // tag 0 != any step s>=1

    seq2seq_2hop<<<NBLK, NTHR, 0, stream>>>(
        en_batch, en_lens, de_batch, en_emb, eWih, eWhh, ebih, ebhh,
        de_emb, dWih, dWhh, dbih, dbhh, fcW, fcb, out, kv, tk);
}